// Round 1
// baseline (328.590 us; speedup 1.0000x reference)
//
#include <hip/hip_runtime.h>

#define NPOS (4*16*64*64)     // 262144 positions (B*D*H*W)
#define KCODES 512
#define CDIM 64
#define CH_STRIDE 65536       // D*H*W element stride between channels
#define OUT_SCALAR_IDX (NPOS * CDIM)  // 16777216

__global__ __launch_bounds__(256) void vq_main(
    const float* __restrict__ z, const float* __restrict__ emb,
    float* __restrict__ out, int* __restrict__ gcounts) {
  __shared__ float s_ee[KCODES];
  __shared__ int s_hist[KCODES];
  const int tid = threadIdx.x;

  // Per-block: precompute ||e_k||^2 into LDS, zero histogram. 512/256 = 2 each.
  for (int k = tid; k < KCODES; k += 256) {
    float acc = 0.f;
    #pragma unroll
    for (int c = 0; c < CDIM; ++c) {
      float e = emb[k * CDIM + c];
      acc = fmaf(e, e, acc);
    }
    s_ee[k] = acc;
    s_hist[k] = 0;
  }
  __syncthreads();

  const int n = blockIdx.x * 256 + tid;      // position index
  const int b = n >> 16;                     // batch (65536 spatial per batch)
  const int sp = n & 65535;                  // spatial index within batch
  const float* zp = z + ((size_t)b << 22) + sp;   // b*C*65536 + sp

  // Load this position's 64-dim vector into registers (coalesced across lanes
  // per channel: consecutive lanes -> consecutive spatial addresses).
  float zv[CDIM];
  #pragma unroll
  for (int c = 0; c < CDIM; ++c) zv[c] = zp[(size_t)c * CH_STRIDE];

  float zz = 0.f;
  #pragma unroll
  for (int c = 0; c < CDIM; ++c) zz = fmaf(zv[c], zv[c], zz);

  // Argmin over codebook. emb accesses are wave-uniform -> scalar loads.
  float dmin = INFINITY;
  int best = 0;
  for (int k = 0; k < KCODES; ++k) {
    float dot = 0.f;
    #pragma unroll
    for (int c = 0; c < CDIM; ++c) dot = fmaf(zv[c], emb[k * CDIM + c], dot);
    // mimic reference rounding: fl(zz - 2*dot) + ee   (2*dot exact, fma = one
    // rounding, identical to the subtraction)
    float d = fmaf(-2.f, dot, zz) + s_ee[k];
    if (d < dmin) { dmin = d; best = k; }   // strict < keeps first index (jnp.argmin)
  }

  // Write quantized vector back in [B,C,D,H,W] layout (coalesced per channel).
  float* op = out + ((size_t)b << 22) + sp;
  const float* ep = emb + best * CDIM;
  #pragma unroll
  for (int c = 0; c < CDIM; ++c) op[(size_t)c * CH_STRIDE] = ep[c];

  // Histogram for unique-code count.
  atomicAdd(&s_hist[best], 1);
  __syncthreads();
  for (int k = tid; k < KCODES; k += 256) {
    int h = s_hist[k];
    if (h) atomicAdd(&gcounts[k], h);
  }
}

__global__ __launch_bounds__(512) void vq_count(
    const int* __restrict__ gcounts, float* __restrict__ out) {
  __shared__ int red[512];
  const int t = threadIdx.x;
  red[t] = (gcounts[t] > 0) ? 1 : 0;
  __syncthreads();
  for (int s = 256; s > 0; s >>= 1) {
    if (t < s) red[t] += red[t + s];
    __syncthreads();
  }
  if (t == 0) out[OUT_SCALAR_IDX] = (float)red[0];
}

extern "C" void kernel_launch(void* const* d_in, const int* in_sizes, int n_in,
                              void* d_out, int out_size, void* d_ws, size_t ws_size,
                              hipStream_t stream) {
  const float* z = (const float*)d_in[0];
  const float* emb = (const float*)d_in[1];
  float* out = (float*)d_out;
  int* gcounts = (int*)d_ws;

  hipMemsetAsync(gcounts, 0, KCODES * sizeof(int), stream);
  vq_main<<<NPOS / 256, 256, 0, stream>>>(z, emb, out, gcounts);
  vq_count<<<1, 512, 0, stream>>>(gcounts, out);
}

// Round 2
// 76.194 us; speedup vs baseline: 4.3125x; 4.3125x over previous
//
#include <hip/hip_runtime.h>

#define NPOS (4*16*64*64)             // 262144 positions
#define KCODES 512
#define CDIM 64
#define OUT_SCALAR_IDX ((size_t)NPOS * CDIM)

typedef short short8 __attribute__((ext_vector_type(8)));
typedef float f32x4 __attribute__((ext_vector_type(4)));

__device__ __forceinline__ ushort f2bf(float f) {
  uint u = __builtin_bit_cast(uint, f);
  u += 0x7fff + ((u >> 16) & 1);        // round-to-nearest-even
  return (ushort)(u >> 16);
}

__global__ __launch_bounds__(256) void vq_mfma(
    const float* __restrict__ z, const float* __restrict__ emb,
    float* __restrict__ out, int* __restrict__ gcounts) {
  __shared__ ushort embs[KCODES * CDIM];   // bf16, XOR-swizzled rows
  __shared__ float s_ee[KCODES];
  __shared__ int s_idx[256];
  __shared__ int s_hist[KCODES];

  const int tid = threadIdx.x;
  const int lane = tid & 63;
  const int w = tid >> 6;

  // ---- Stage emb -> LDS: bf16 swizzled + fp32 ||e||^2 ----
  for (int r = tid; r < KCODES; r += 256) {
    const float4* er = (const float4*)(emb + r * CDIM);
    float ee = 0.f;
    #pragma unroll
    for (int q = 0; q < 8; ++q) {               // 16B bf16 chunk = 8 channels
      float4 x = er[2 * q], y = er[2 * q + 1];
      ee = fmaf(x.x, x.x, ee); ee = fmaf(x.y, x.y, ee);
      ee = fmaf(x.z, x.z, ee); ee = fmaf(x.w, x.w, ee);
      ee = fmaf(y.x, y.x, ee); ee = fmaf(y.y, y.y, ee);
      ee = fmaf(y.z, y.z, ee); ee = fmaf(y.w, y.w, ee);
      uint4 ch;
      ch.x = f2bf(x.x) | ((uint)f2bf(x.y) << 16);
      ch.y = f2bf(x.z) | ((uint)f2bf(x.w) << 16);
      ch.z = f2bf(y.x) | ((uint)f2bf(y.y) << 16);
      ch.w = f2bf(y.z) | ((uint)f2bf(y.w) << 16);
      *(uint4*)((char*)embs + ((r * 128 + q * 16) ^ ((r & 7) << 4))) = ch;
    }
    s_ee[r] = ee;
    s_hist[r] = 0;
  }

  // ---- A fragments: 4 row-tiles x (K=64 as two K=32 halves), bf16 in regs ----
  // mfma_f32_16x16x32_bf16 A layout: row = lane&15, k = (lane>>4)*8 + j (consecutive)
  const int kg = lane >> 4;          // k-group 0..3
  const int arow = lane & 15;
  short8 af[4][2];
  #pragma unroll
  for (int rt = 0; rt < 4; ++rt) {
    const int n = blockIdx.x * 256 + w * 64 + rt * 16 + arow;
    const int b = n >> 16, sp = n & 65535;
    const float* zp = z + ((size_t)b << 22) + sp;
    #pragma unroll
    for (int h = 0; h < 2; ++h) {
      float v[8];
      #pragma unroll
      for (int j = 0; j < 8; ++j)
        v[j] = zp[(size_t)(h * 32 + kg * 8 + j) << 16];
      short8 f;
      #pragma unroll
      for (int j = 0; j < 8; ++j) f[j] = (short)f2bf(v[j]);
      af[rt][h] = f;
    }
  }

  __syncthreads();   // emb LDS ready

  // ---- Main loop over 32 code-tiles of 16 codes ----
  float minv[4][4];
  int minct[4][4];
  #pragma unroll
  for (int rt = 0; rt < 4; ++rt)
    #pragma unroll
    for (int s = 0; s < 4; ++s) { minv[rt][s] = 3.4e38f; minct[rt][s] = 0; }

  const f32x4 zf = {0.f, 0.f, 0.f, 0.f};
  const int swz = (lane & 7) << 4;
  const int lbase = (lane & 15) * 128 + kg * 16;   // byte offset pre-swizzle

  #pragma unroll 8
  for (int ct = 0; ct < 32; ++ct) {
    const char* p = (const char*)embs + ct * 2048;
    short8 b0 = *(const short8*)(p + ((lbase + 0) ^ swz));
    short8 b1 = *(const short8*)(p + ((lbase + 64) ^ swz));
    float eev = s_ee[ct * 16 + (lane & 15)];
    #pragma unroll
    for (int rt = 0; rt < 4; ++rt) {
      f32x4 acc = __builtin_amdgcn_mfma_f32_16x16x32_bf16(af[rt][0], b0, zf, 0, 0, 0);
      acc = __builtin_amdgcn_mfma_f32_16x16x32_bf16(af[rt][1], b1, acc, 0, 0, 0);
      #pragma unroll
      for (int s = 0; s < 4; ++s) {
        float d = fmaf(-2.f, acc[s], eev);
        bool lt = d < minv[rt][s];               // strict <: first tile wins ties
        minv[rt][s] = lt ? d : minv[rt][s];
        minct[rt][s] = lt ? ct : minct[rt][s];
      }
    }
  }

  // ---- Per-row argmin across the 16 cols (C layout: col=lane&15,
  //      row=(lane>>4)*4+reg) via shfl_xor butterfly over the 16-lane group ----
  #pragma unroll
  for (int rt = 0; rt < 4; ++rt) {
    #pragma unroll
    for (int s = 0; s < 4; ++s) {
      float v = minv[rt][s];
      int idx = minct[rt][s] * 16 + (lane & 15);
      #pragma unroll
      for (int m = 1; m < 16; m <<= 1) {
        float pv = __shfl_xor(v, m, 64);
        int pi = __shfl_xor(idx, m, 64);
        bool t = (pv < v) || (pv == v && pi < idx);  // lower index wins ties
        v = t ? pv : v;
        idx = t ? pi : idx;
      }
      if ((lane & 15) == 0)
        s_idx[w * 64 + rt * 16 + (lane >> 4) * 4 + s] = idx;
    }
  }
  __syncthreads();

  // ---- Epilogue: exact fp32 emb gather (L2-resident) + coalesced write ----
  const int myidx = s_idx[tid];
  atomicAdd(&s_hist[myidx], 1);
  {
    const int n = blockIdx.x * 256 + tid;
    const int b = n >> 16, sp = n & 65535;
    float* op = out + ((size_t)b << 22) + sp;
    const float4* ef = (const float4*)(emb + myidx * CDIM);
    #pragma unroll
    for (int q = 0; q < 16; ++q) {
      float4 e4 = ef[q];
      op[(size_t)(4 * q + 0) << 16] = e4.x;
      op[(size_t)(4 * q + 1) << 16] = e4.y;
      op[(size_t)(4 * q + 2) << 16] = e4.z;
      op[(size_t)(4 * q + 3) << 16] = e4.w;
    }
  }
  __syncthreads();
  for (int k = tid; k < KCODES; k += 256) {
    int h = s_hist[k];
    if (h) atomicAdd(&gcounts[k], h);
  }
}

__global__ __launch_bounds__(512) void vq_count(
    const int* __restrict__ gcounts, float* __restrict__ out) {
  __shared__ int red[512];
  const int t = threadIdx.x;
  red[t] = (gcounts[t] > 0) ? 1 : 0;
  __syncthreads();
  for (int s = 256; s > 0; s >>= 1) {
    if (t < s) red[t] += red[t + s];
    __syncthreads();
  }
  if (t == 0) out[OUT_SCALAR_IDX] = (float)red[0];
}

extern "C" void kernel_launch(void* const* d_in, const int* in_sizes, int n_in,
                              void* d_out, int out_size, void* d_ws, size_t ws_size,
                              hipStream_t stream) {
  const float* z = (const float*)d_in[0];
  const float* emb = (const float*)d_in[1];
  float* out = (float*)d_out;
  int* gcounts = (int*)d_ws;

  hipMemsetAsync(gcounts, 0, KCODES * sizeof(int), stream);
  vq_mfma<<<NPOS / 256, 256, 0, stream>>>(z, emb, out, gcounts);
  vq_count<<<1, 512, 0, stream>>>(gcounts, out);
}

// Round 3
// 52.160 us; speedup vs baseline: 6.2996x; 1.4608x over previous
//
#include <hip/hip_runtime.h>

#define NPOS (4*16*64*64)             // 262144 positions
#define KCODES 512
#define CDIM 64
#define OUT_SCALAR_IDX ((size_t)NPOS * CDIM)

// d_ws layout
#define WS_GCOUNT 0                   // 512 * int
#define WS_EMB    4096                // 65536 B: pre-swizzled (-2*e) bf16 image
#define WS_EE     (4096 + 65536)      // 512 * float: ||e||^2

typedef short short8 __attribute__((ext_vector_type(8)));
typedef float f32x4 __attribute__((ext_vector_type(4)));

__device__ __forceinline__ ushort f2bf(float f) {
  uint u = __builtin_bit_cast(uint, f);
  u += 0x7fff + ((u >> 16) & 1);        // RNE
  return (ushort)(u >> 16);
}

// ---- prep: codebook -> pre-swizzled -2x bf16 image + ee table + zero gcounts
__global__ __launch_bounds__(64) void vq_prep(
    const float* __restrict__ emb, char* __restrict__ ws) {
  const int r = blockIdx.x * 64 + threadIdx.x;     // 8 blocks x 64 = 512 rows
  ((int*)(ws + WS_GCOUNT))[r] = 0;
  const float4* er = (const float4*)(emb + r * CDIM);
  char* img = ws + WS_EMB;
  float ee = 0.f;
  #pragma unroll
  for (int q = 0; q < 8; ++q) {
    float4 x = er[2 * q], y = er[2 * q + 1];
    ee = fmaf(x.x, x.x, ee); ee = fmaf(x.y, x.y, ee);
    ee = fmaf(x.z, x.z, ee); ee = fmaf(x.w, x.w, ee);
    ee = fmaf(y.x, y.x, ee); ee = fmaf(y.y, y.y, ee);
    ee = fmaf(y.z, y.z, ee); ee = fmaf(y.w, y.w, ee);
    uint4 ch;
    ch.x = f2bf(-2.f * x.x) | ((uint)f2bf(-2.f * x.y) << 16);
    ch.y = f2bf(-2.f * x.z) | ((uint)f2bf(-2.f * x.w) << 16);
    ch.z = f2bf(-2.f * y.x) | ((uint)f2bf(-2.f * y.y) << 16);
    ch.w = f2bf(-2.f * y.z) | ((uint)f2bf(-2.f * y.w) << 16);
    *(uint4*)(img + ((r * 128 + q * 16) ^ ((r & 7) << 4))) = ch;
  }
  ((float*)(ws + WS_EE))[r] = ee;
}

__global__ __launch_bounds__(512, 4) void vq_mfma(
    const float* __restrict__ z, const float* __restrict__ emb,
    const char* __restrict__ ws, float* __restrict__ out,
    int* __restrict__ gcounts) {
  __shared__ ushort embs[KCODES * CDIM];   // 64 KB swizzled -2x bf16
  __shared__ float s_ee[KCODES];
  __shared__ int s_idx[512];
  __shared__ int s_hist[KCODES];

  const int tid = threadIdx.x;
  const int lane = tid & 63;
  const int w = tid >> 6;
  const int col = lane & 15;
  const int kg = lane >> 4;

  // ---- async DMA: pre-swizzled image -> LDS (linear dest = lane order) ----
  {
    const char* src = ws + WS_EMB;
    #pragma unroll
    for (int i = 0; i < 8; ++i) {
      const int byteoff = (i * 512 + tid) * 16;
      __builtin_amdgcn_global_load_lds(
          (const __attribute__((address_space(1))) void*)(src + byteoff),
          (__attribute__((address_space(3))) void*)((char*)embs + byteoff),
          16, 0, 0);
    }
    if (tid < 128) {
      __builtin_amdgcn_global_load_lds(
          (const __attribute__((address_space(1))) void*)(ws + WS_EE + tid * 16),
          (__attribute__((address_space(3))) void*)((char*)s_ee + tid * 16),
          16, 0, 0);
    }
  }
  s_hist[tid] = 0;

  // ---- A fragments: 4 row-tiles x 2 K-halves, bf16 (hides under DMA) ----
  short8 af[4][2];
  const int nb = blockIdx.x * 512 + w * 64;
  #pragma unroll
  for (int rt = 0; rt < 4; ++rt) {
    const int n = nb + rt * 16 + col;
    const int b = n >> 16, sp = n & 65535;
    const float* zp = z + ((size_t)b << 22) + sp;
    #pragma unroll
    for (int h = 0; h < 2; ++h) {
      short8 f;
      #pragma unroll
      for (int j = 0; j < 8; ++j)
        f[j] = (short)f2bf(zp[(size_t)(h * 32 + kg * 8 + j) << 16]);
      af[rt][h] = f;
    }
  }

  __syncthreads();   // drains DMA (vmcnt) + hist zero

  // ---- main loop: 32 code-tiles; acc = ee + (-2e). z  (distance direct) ----
  float minv[4][4];
  int minct[4][4];
  #pragma unroll
  for (int rt = 0; rt < 4; ++rt)
    #pragma unroll
    for (int s = 0; s < 4; ++s) { minv[rt][s] = 3.4e38f; minct[rt][s] = 0; }

  const int swz = (lane & 7) << 4;
  const int lbase = col * 128 + kg * 16;

  #pragma unroll 8
  for (int ct = 0; ct < 32; ++ct) {
    const char* p = (const char*)embs + ct * 2048;
    short8 b0 = *(const short8*)(p + ((lbase + 0) ^ swz));
    short8 b1 = *(const short8*)(p + ((lbase + 64) ^ swz));
    const float eev = s_ee[ct * 16 + col];
    const f32x4 cin = {eev, eev, eev, eev};
    #pragma unroll
    for (int rt = 0; rt < 4; ++rt) {
      f32x4 acc = __builtin_amdgcn_mfma_f32_16x16x32_bf16(af[rt][0], b0, cin, 0, 0, 0);
      acc = __builtin_amdgcn_mfma_f32_16x16x32_bf16(af[rt][1], b1, acc, 0, 0, 0);
      #pragma unroll
      for (int s = 0; s < 4; ++s) {
        bool lt = acc[s] < minv[rt][s];          // strict <: first tile wins
        minv[rt][s] = lt ? acc[s] : minv[rt][s];
        minct[rt][s] = lt ? ct : minct[rt][s];
      }
    }
  }

  // ---- per-row argmin across 16 cols: sortable-uint key, idx in low 9 bits ----
  #pragma unroll
  for (int rt = 0; rt < 4; ++rt) {
    #pragma unroll
    for (int s = 0; s < 4; ++s) {
      uint f = __builtin_bit_cast(uint, minv[rt][s]);
      uint key = f ^ ((uint)((int)f >> 31) | 0x80000000u);
      key = (key & 0xFFFFFE00u) | (uint)(minct[rt][s] * 16 + col);
      #pragma unroll
      for (int m = 1; m < 16; m <<= 1) {
        uint o = (uint)__shfl_xor((int)key, m, 64);
        key = o < key ? o : key;
      }
      if (col == 0)
        s_idx[w * 64 + rt * 16 + kg * 4 + s] = (int)(key & 0x1FFu);
    }
  }
  __syncthreads();

  // ---- epilogue: exact fp32 emb gather (L2-hot) + coalesced strided write ----
  const int myidx = s_idx[tid];
  atomicAdd(&s_hist[myidx], 1);
  {
    const int n = blockIdx.x * 512 + tid;
    const int b = n >> 16, sp = n & 65535;
    float* op = out + ((size_t)b << 22) + sp;
    const float4* ef = (const float4*)(emb + myidx * CDIM);
    #pragma unroll
    for (int q = 0; q < 16; ++q) {
      float4 e4 = ef[q];
      op[(size_t)(4 * q + 0) << 16] = e4.x;
      op[(size_t)(4 * q + 1) << 16] = e4.y;
      op[(size_t)(4 * q + 2) << 16] = e4.z;
      op[(size_t)(4 * q + 3) << 16] = e4.w;
    }
  }
  __syncthreads();
  {
    int h = s_hist[tid];
    if (h) atomicAdd(&gcounts[tid], h);
  }
}

__global__ __launch_bounds__(512) void vq_count(
    const int* __restrict__ gcounts, float* __restrict__ out) {
  __shared__ int red[512];
  const int t = threadIdx.x;
  red[t] = (gcounts[t] > 0) ? 1 : 0;
  __syncthreads();
  for (int s = 256; s > 0; s >>= 1) {
    if (t < s) red[t] += red[t + s];
    __syncthreads();
  }
  if (t == 0) out[OUT_SCALAR_IDX] = (float)red[0];
}

extern "C" void kernel_launch(void* const* d_in, const int* in_sizes, int n_in,
                              void* d_out, int out_size, void* d_ws, size_t ws_size,
                              hipStream_t stream) {
  const float* z = (const float*)d_in[0];
  const float* emb = (const float*)d_in[1];
  float* out = (float*)d_out;
  char* ws = (char*)d_ws;
  int* gcounts = (int*)(ws + WS_GCOUNT);

  vq_prep<<<8, 64, 0, stream>>>(emb, ws);
  vq_mfma<<<NPOS / 512, 512, 0, stream>>>(z, emb, ws, out, gcounts);
  vq_count<<<1, 512, 0, stream>>>(gcounts, out);
}